// Round 2
// baseline (374.198 us; speedup 1.0000x reference)
//
#include <hip/hip_runtime.h>

#define NB 262144
#define AA 10
#define DD 10
#define KK 32

typedef float v2f __attribute__((ext_vector_type(2)));

// ---- packed f32 math (guaranteed v_pk_* emission) ---------------------------
static __device__ __forceinline__ v2f mk2(float a, float b) {
    v2f r; r.x = a; r.y = b; return r;
}
static __device__ __forceinline__ v2f pk_fma(v2f a, v2f b, v2f c) {
    v2f d; asm("v_pk_fma_f32 %0, %1, %2, %3" : "=v"(d) : "v"(a), "v"(b), "v"(c)); return d;
}
// uniform (SGPR-pair) first operand: weights feed the FMA straight from SMEM
static __device__ __forceinline__ v2f pk_fma_s(v2f sa, v2f b, v2f c) {
    v2f d; asm("v_pk_fma_f32 %0, %1, %2, %3" : "=v"(d) : "s"(sa), "v"(b), "v"(c)); return d;
}
static __device__ __forceinline__ v2f pk_mul(v2f a, v2f b) {
    v2f d; asm("v_pk_mul_f32 %0, %1, %2" : "=v"(d) : "v"(a), "v"(b)); return d;
}
static __device__ __forceinline__ v2f pk_mul_s(v2f sa, v2f b) {
    v2f d; asm("v_pk_mul_f32 %0, %1, %2" : "=v"(d) : "s"(sa), "v"(b)); return d;
}
static __device__ __forceinline__ v2f pk_add(v2f a, v2f b) {
    v2f d; asm("v_pk_add_f32 %0, %1, %2" : "=v"(d) : "v"(a), "v"(b)); return d;
}

// ---- bf16 helpers -----------------------------------------------------------
static __device__ __forceinline__ float b2f(unsigned short h) {
    union { unsigned u; float f; } c; c.u = ((unsigned)h) << 16; return c.f;
}
static __device__ __forceinline__ float bflo(unsigned w) {
    union { unsigned u; float f; } c; c.u = w << 16; return c.f;
}
static __device__ __forceinline__ float bfhi(unsigned w) {
    union { unsigned u; float f; } c; c.u = w & 0xffff0000u; return c.f;
}

// f32-vs-bf16 detection by exponent-field statistics (verified earlier rounds).
__device__ __forceinline__ int detect_f32(const unsigned short* p, int nshorts,
                                          unsigned expthr, int lane) {
    int bad = 0;
    if (lane < nshorts) {
        unsigned e = (p[lane] >> 7) & 0xFFu;
        bad = (e >= expthr);
    }
    return __any(bad);
}

// ---- prep: convert + pack weights into workspace ----------------------------
// wf layout (floats):
//   [0:100)            M row-major
//   [128 + k*24)       user row k: Pu[k][0..9] | Pi[k][0..9] | pu[k] | pad3
//   [896 + k*24)       item row k: Pi[k][0..9] | Pu[k][0..9] | pi[k] | pad3
__global__ __launch_bounds__(64) void prep_weights(
    const unsigned short* __restrict__ wM,
    const unsigned short* __restrict__ wPu,
    const unsigned short* __restrict__ wpu,
    const unsigned short* __restrict__ wPi,
    const unsigned short* __restrict__ wpi,
    float* __restrict__ wf)
{
    const int t = threadIdx.x;
    int f = 0;
    f |= detect_f32(wM,  64, 125, t) << 0;
    f |= detect_f32(wPu, 64, 125, t) << 1;
    f |= detect_f32(wpu, 32, 125, t) << 2;
    f |= detect_f32(wPi, 64, 125, t) << 3;
    f |= detect_f32(wpi, 32, 125, t) << 4;
    const float* fM  = (const float*)wM;
    const float* fPu = (const float*)wPu;
    const float* fpu = (const float*)wpu;
    const float* fPi = (const float*)wPi;
    const float* fpi = (const float*)wpi;

    for (int i = t; i < 100; i += 64) wf[i] = (f & 1) ? fM[i] : b2f(wM[i]);

    for (int i = t; i < KK * 24; i += 64) {
        const int k = i / 24, j = i % 24;
        float vu = 0.f, vi = 0.f;
        if (j < 10) {
            vu = (f & 2) ? fPu[k * 10 + j] : b2f(wPu[k * 10 + j]);
            vi = (f & 8) ? fPi[k * 10 + j] : b2f(wPi[k * 10 + j]);
        } else if (j < 20) {
            vu = (f & 8) ? fPi[k * 10 + j - 10] : b2f(wPi[k * 10 + j - 10]);
            vi = (f & 2) ? fPu[k * 10 + j - 10] : b2f(wPu[k * 10 + j - 10]);
        } else if (j == 20) {
            vu = (f & 4)  ? fpu[k] : b2f(wpu[k]);
            vi = (f & 16) ? fpi[k] : b2f(wpi[k]);
        }
        wf[128 + i] = vu;
        wf[896 + i] = vi;
    }
}

// ---- input loader: one batch row (100 elems) -> 50 f32 pairs ----------------
static __device__ __forceinline__ void load_rep(const unsigned short* __restrict__ p,
                                                int isf32, long long b, v2f R[AA][5]) {
    if (isf32) {
        const float4* g = (const float4*)((const float*)p + b * 100);
        #pragma unroll
        for (int j = 0; j < 25; j++) {
            float4 w = g[j];
            int e = 2 * j;
            R[e / 5][e % 5]             = mk2(w.x, w.y);
            R[(e + 1) / 5][(e + 1) % 5] = mk2(w.z, w.w);
        }
    } else {
        const uint2* g = (const uint2*)(p + b * 100);
        #pragma unroll
        for (int j = 0; j < 25; j++) {
            uint2 w = g[j];
            int e = 2 * j;
            R[e / 5][e % 5]             = mk2(bflo(w.x), bfhi(w.x));
            R[(e + 1) / 5][(e + 1) % 5] = mk2(bflo(w.y), bfhi(w.y));
        }
    }
}

// ---- main kernel -------------------------------------------------------------
// One thread per batch. Schedule (peak live ~235 VGPR, no AGPR/scratch traffic):
//  P1/P2 load V,U -> regs
//  P3    per u: um = U[u]*M (M via SGPR); Wrow = sum_v relu(um*V[v]) V[v];
//        stash Wrow -> thread-private LDS       [U,V live]
//  P4    V dies; read W back to regs; USER k-OUTER loop:
//        per k load 21 weight floats ONCE (SGPR), inner u=0..9   [U,W live]
//  P5    softmax -> direct global stores
//  P6    reload V from global (L3-resident)     [U,V live]
//  P7    per v: mv = M*V[v]; Xrow = sum_u relu(U[u]*mv) U[u]; stash -> LDS
//  P8    U dies; read X back; ITEM k-OUTER loop [V,X live]
//  P9    softmax -> direct global stores
// No barriers anywhere (stash is thread-private).
__global__ __launch_bounds__(64, 2) void aie_main(
    const unsigned short* __restrict__ user_rep,
    const unsigned short* __restrict__ item_rep,
    const float* __restrict__ wf,
    float* __restrict__ out)
{
    __shared__ v2f stash[64 * 51];   // 25.5 KB; stride 51 (odd*3 mod 16 -> even b64 banking)
    const int t = threadIdx.x;
    const long long b = (long long)blockIdx.x * 64 + t;
    v2f* my = &stash[t * 51];

    const int fu = detect_f32(user_rep, 64, 137, t);
    const int fi = detect_f32(item_rep, 64, 137, t);

    v2f U2[AA][5], V2[AA][5];
    load_rep(item_rep, fi, b, V2);
    load_rep(user_rep, fu, b, U2);

    const v2f* M2 = (const v2f*)wf;   // M2[d*5+j] = M[d][2j..2j+1], uniform -> SGPR

    // ---- P3: W rows -> stash ----
    #pragma unroll
    for (int u = 0; u < AA; u++) {
        v2f um2[5];
        {
            v2f xs = mk2(U2[u][0].x, U2[u][0].x);
            #pragma unroll
            for (int j = 0; j < 5; j++) um2[j] = pk_mul_s(M2[j], xs);
        }
        #pragma unroll
        for (int d = 1; d < DD; d++) {
            const float x = (d & 1) ? U2[u][d >> 1].y : U2[u][d >> 1].x;
            v2f xs = mk2(x, x);
            #pragma unroll
            for (int j = 0; j < 5; j++) um2[j] = pk_fma_s(M2[d * 5 + j], xs, um2[j]);
        }
        v2f Wr[5];
        #pragma unroll
        for (int j = 0; j < 5; j++) Wr[j] = mk2(0.f, 0.f);
        #pragma unroll
        for (int v = 0; v < AA; v++) {
            v2f r2 = pk_mul(um2[0], V2[v][0]);
            #pragma unroll
            for (int j = 1; j < 5; j++) r2 = pk_fma(um2[j], V2[v][j], r2);
            const float r = fmaxf(r2.x + r2.y, 0.f);
            v2f rs = mk2(r, r);
            #pragma unroll
            for (int j = 0; j < 5; j++) Wr[j] = pk_fma(rs, V2[v][j], Wr[j]);
        }
        #pragma unroll
        for (int j = 0; j < 5; j++) my[u * 5 + j] = Wr[j];
    }
    asm volatile("" ::: "memory");   // block LDS store->load forwarding (keeps regs low)

    // ---- P4: user k-outer ----
    v2f Wf[AA][5];
    #pragma unroll
    for (int u = 0; u < AA; u++)
        #pragma unroll
        for (int j = 0; j < 5; j++) Wf[u][j] = my[u * 5 + j];

    float us[AA];
    #pragma unroll
    for (int u = 0; u < AA; u++) us[u] = 0.f;
    #pragma unroll 2
    for (int k = 0; k < KK; k++) {
        const v2f* wk = (const v2f*)(wf + 128 + k * 24);  // [0..4]=Pu, [5..9]=Pi
        const float pw = wf[128 + k * 24 + 20];
        #pragma unroll
        for (int u = 0; u < AA; u++) {
            v2f a2 = pk_mul_s(wk[0], U2[u][0]);
            v2f c2 = pk_mul_s(wk[5], Wf[u][0]);
            #pragma unroll
            for (int j = 1; j < 5; j++) {
                a2 = pk_fma_s(wk[j],     U2[u][j], a2);
                c2 = pk_fma_s(wk[5 + j], Wf[u][j], c2);
            }
            v2f s2 = pk_add(a2, c2);
            us[u] += pw * fmaxf(s2.x + s2.y, 0.f);
        }
    }

    // ---- P5: softmax + direct stores ----
    {
        float mx = us[0];
        #pragma unroll
        for (int u = 1; u < AA; u++) mx = fmaxf(mx, us[u]);
        float s = 0.f;
        #pragma unroll
        for (int u = 0; u < AA; u++) { us[u] = __expf(us[u] - mx); s += us[u]; }
        const float inv = 1.f / s;
        float* o0 = out + b * 10;
        #pragma unroll
        for (int j = 0; j < 5; j++)
            *(float2*)(o0 + 2 * j) = make_float2(us[2 * j] * inv, us[2 * j + 1] * inv);
    }

    // ---- P6: reload V (L3-resident) ----
    load_rep(item_rep, fi, b, V2);

    // ---- P7: X rows -> stash ----
    #pragma unroll
    for (int v = 0; v < AA; v++) {
        v2f mv2[5];
        #pragma unroll
        for (int dp = 0; dp < 5; dp++) {
            v2f s0 = pk_mul_s(M2[(2 * dp) * 5],     V2[v][0]);
            v2f s1 = pk_mul_s(M2[(2 * dp + 1) * 5], V2[v][0]);
            #pragma unroll
            for (int j = 1; j < 5; j++) {
                s0 = pk_fma_s(M2[(2 * dp) * 5 + j],     V2[v][j], s0);
                s1 = pk_fma_s(M2[(2 * dp + 1) * 5 + j], V2[v][j], s1);
            }
            mv2[dp] = mk2(s0.x + s0.y, s1.x + s1.y);
        }
        v2f Xr[5];
        #pragma unroll
        for (int j = 0; j < 5; j++) Xr[j] = mk2(0.f, 0.f);
        #pragma unroll
        for (int u = 0; u < AA; u++) {
            v2f r2 = pk_mul(mv2[0], U2[u][0]);
            #pragma unroll
            for (int j = 1; j < 5; j++) r2 = pk_fma(mv2[j], U2[u][j], r2);
            const float r = fmaxf(r2.x + r2.y, 0.f);
            v2f rs = mk2(r, r);
            #pragma unroll
            for (int j = 0; j < 5; j++) Xr[j] = pk_fma(rs, U2[u][j], Xr[j]);
        }
        #pragma unroll
        for (int j = 0; j < 5; j++) my[v * 5 + j] = Xr[j];
    }
    asm volatile("" ::: "memory");

    // ---- P8: item k-outer ----
    v2f Xf[AA][5];
    #pragma unroll
    for (int v = 0; v < AA; v++)
        #pragma unroll
        for (int j = 0; j < 5; j++) Xf[v][j] = my[v * 5 + j];

    float isc[AA];
    #pragma unroll
    for (int v = 0; v < AA; v++) isc[v] = 0.f;
    #pragma unroll 2
    for (int k = 0; k < KK; k++) {
        const v2f* wk = (const v2f*)(wf + 896 + k * 24);  // [0..4]=Pi, [5..9]=Pu
        const float pw = wf[896 + k * 24 + 20];
        #pragma unroll
        for (int v = 0; v < AA; v++) {
            v2f a2 = pk_mul_s(wk[0], V2[v][0]);
            v2f c2 = pk_mul_s(wk[5], Xf[v][0]);
            #pragma unroll
            for (int j = 1; j < 5; j++) {
                a2 = pk_fma_s(wk[j],     V2[v][j], a2);
                c2 = pk_fma_s(wk[5 + j], Xf[v][j], c2);
            }
            v2f s2 = pk_add(a2, c2);
            isc[v] += pw * fmaxf(s2.x + s2.y, 0.f);
        }
    }

    // ---- P9: softmax + direct stores ----
    {
        float mx = isc[0];
        #pragma unroll
        for (int v = 1; v < AA; v++) mx = fmaxf(mx, isc[v]);
        float s = 0.f;
        #pragma unroll
        for (int v = 0; v < AA; v++) { isc[v] = __expf(isc[v] - mx); s += isc[v]; }
        const float inv = 1.f / s;
        float* o1 = out + (size_t)NB * 10 + b * 10;
        #pragma unroll
        for (int j = 0; j < 5; j++)
            *(float2*)(o1 + 2 * j) = make_float2(isc[2 * j] * inv, isc[2 * j + 1] * inv);
    }
}

extern "C" void kernel_launch(void* const* d_in, const int* in_sizes, int n_in,
                              void* d_out, int out_size, void* d_ws, size_t ws_size,
                              hipStream_t stream) {
    const unsigned short* user_rep = (const unsigned short*)d_in[0];
    const unsigned short* item_rep = (const unsigned short*)d_in[1];
    float* wf = (float*)d_ws;

    hipLaunchKernelGGL(prep_weights, dim3(1), dim3(64), 0, stream,
                       (const unsigned short*)d_in[2], (const unsigned short*)d_in[3],
                       (const unsigned short*)d_in[4], (const unsigned short*)d_in[5],
                       (const unsigned short*)d_in[6], wf);

    hipLaunchKernelGGL(aie_main, dim3(NB / 64), dim3(64), 0, stream,
                       user_rep, item_rep, wf, (float*)d_out);
}